// Round 5
// baseline (211.267 us; speedup 1.0000x reference)
//
#include <hip/hip_runtime.h>
#include <hip/hip_bf16.h>
#include <stdint.h>

typedef unsigned short u16;
typedef __attribute__((ext_vector_type(8))) short short8;
typedef __attribute__((ext_vector_type(4))) float floatx4;

#define N_IMG 4
#define C_IN  2048
#define HW    1024
#define KK    9
#define O_OUT 256
#define NPIX  4096          // N_IMG*HW
#define M_PAD  2560         // 16 M-tiles x 160 rows (2304 proj + 81 conv + pad)
#define H_ROWS 2432         // H rows actually stored (proj 2304 + conv 81 + pad)
#define K_DIM  2048
#define BN_EPS 1e-5f

// workspace offsets (bytes), 256-aligned
#define OFF_A    0u                // A: 2560*2048*2 = 10485760
#define OFF_XT   10485760u         // XT: 4096*2048*2 = 16777216
#define OFF_H    27262976u         // H: 2432*4096*2 = 19922944
#define OFF_SRAW 47185920u         // sraw: 36864*4
#define OFF_STAT 47333376u

// fp32 -> bf16 bits, round-to-nearest-even
__device__ __forceinline__ u16 f2b(float f) {
    unsigned u = __float_as_uint(f);
    return (u16)((u + 0x7FFFu + ((u >> 16) & 1u)) >> 16);
}

__device__ __forceinline__ void load8f(const float* base, size_t eidx, u16* out) {
    const float* p = base + eidx;
    float4 a = ((const float4*)p)[0];
    float4 b = ((const float4*)p)[1];
    float f[8] = {a.x, a.y, a.z, a.w, b.x, b.y, b.z, b.w};
#pragma unroll
    for (int j = 0; j < 8; ++j) out[j] = f2b(f[j]);
}

// ---------------- merged staging kernel (R10-validated, unchanged) ----------------
__global__ void build_all(const float* __restrict__ x, const float* __restrict__ wgt,
                          const float* __restrict__ cw, u16* __restrict__ xt,
                          u16* __restrict__ A, float* __restrict__ stats) {
    __shared__ __align__(16) u16 lds[9 * 2056];
    int b = blockIdx.x, t = threadIdx.x;
    if (b < 2048) {
        int c0 = (b & 31) * 64, p0 = ((b >> 5) & 15) * 64, n = b >> 9;
        int rp = t >> 3;                // channel-pair 0..31
        int pv = (t & 7) * 8;           // pixel group
        u16 h0[8], h1[8];
        load8f(x, (size_t)(n * C_IN + c0 + 2 * rp) * HW + p0 + pv, h0);
        load8f(x, (size_t)(n * C_IN + c0 + 2 * rp + 1) * HW + p0 + pv, h1);
        unsigned* l32 = (unsigned*)lds;   // [64 pixels][stride 35 u32]
#pragma unroll
        for (int j = 0; j < 8; ++j)
            l32[(pv + j) * 35 + rp] = (unsigned)h0[j] | ((unsigned)h1[j] << 16);
        __syncthreads();
        int pr = t >> 3, cq = (t & 7) * 4;   // pixel, u32-quad (8 channels)
        unsigned o0[4], o1[4];
#pragma unroll
        for (int i = 0; i < 4; ++i) {
            o0[i] = l32[pr * 35 + cq + i];
            o1[i] = l32[(pr + 32) * 35 + cq + i];
        }
        *(uint4*)(xt + (size_t)(n * HW + p0 + pr) * K_DIM + c0 + cq * 2) = *(uint4*)o0;
        *(uint4*)(xt + (size_t)(n * HW + p0 + pr + 32) * K_DIM + c0 + cq * 2) = *(uint4*)o1;
    } else if (b < 2304) {
        int o = b - 2048;
        size_t base = (size_t)o * 18432;   // weight[o][c][l], e = c*9+l
        for (int i = 0; i < 9; ++i) {
            int e0 = (t + i * 256) * 8;
            u16 hv[8];
            load8f(wgt, base + e0, hv);
#pragma unroll
            for (int j = 0; j < 8; ++j) {
                int e = e0 + j;
                int c = e / 9, l = e - c * 9;
                lds[l * 2056 + c] = hv[j];
            }
        }
        __syncthreads();
        for (int l = 0; l < 9; ++l) {
            size_t row = (size_t)l * 256 + o;
            *(uint4*)(A + row * K_DIM + t * 8) = *(const uint4*)&lds[l * 2056 + t * 8];
        }
    } else if (b < 2313) {
        int l = b - 2304;
        size_t base = (size_t)l * 18432;    // conv_w[l][c][k], e = c*9+k
        for (int i = 0; i < 9; ++i) {
            int e0 = (t + i * 256) * 8;
            u16 hv[8];
            load8f(cw, base + e0, hv);
#pragma unroll
            for (int j = 0; j < 8; ++j) {
                int e = e0 + j;
                int c = e / 9, k = e - c * 9;
                lds[k * 2056 + c] = hv[j];
            }
        }
        __syncthreads();
        for (int k = 0; k < 9; ++k) {
            size_t row = 2304 + (size_t)k * 9 + l;
            *(uint4*)(A + row * K_DIM + t * 8) = *(const uint4*)&lds[k * 2056 + t * 8];
        }
    } else {
        // zero A rows 2385..2431 (rows 2432..2559 are garbage; each H row
        // depends only on its own A row and rows >=2432 are never stored;
        // garbage/valid rows never share an MFMA fragment since 2432%16==0)
        uint4 z = {0, 0, 0, 0};
        uint4* dst = (uint4*)(A + (size_t)2385 * K_DIM);
        for (int i = t; i < (47 * 2048) / 8; i += 256) dst[i] = z;
        if (t < 18) stats[t] = 0.0f;
    }
}

// ---------------- GEMM: H = A * XT^T ----------------
// R15: 160x256 tile, BK=64, 8 waves (2Mx4N), grid 256. A bypasses LDS:
// MFMA A-fragments loaded global->register (double-buffered, 1 tile ahead).
// R4 diagnosis: LDS traffic (A+B reads 144KB + DMA 52KB per K-tile per CU
// ~ 2150cyc) exceeded the MFMA bound (1553cyc) -> LDS-BW-bound regardless
// of schedule. A-direct cuts LDS to 96KB (B only) < MFMA bound. A-fragment
// addresses: 4 lanes (q) read consecutive 16B of one row (clean 64B
// segments); the 4 waves of a wave-row read IDENTICAL addresses (4x L1
// reuse of a 20KB K-slice). vmcnt ledger: invariant 14 outstanding
// (4 B-DMA + 10 A-loads) at each iter boundary; VMW(14) drains exactly
// the previous tile's A+B.
__device__ __forceinline__ void gload_lds16(const void* g, void* l) {
    __builtin_amdgcn_global_load_lds((__attribute__((address_space(1))) void*)(g),
                                     (__attribute__((address_space(3))) void*)(l), 16, 0, 0);
}

// B half-tile hh (128 rows): wave w covers rows hh*128 + w*16 .. +15 via 2 loads
#define STG_B(bb, hh, kt) do {                                                               \
    gload_lds16(gB0 + (size_t)((hh) * 128 + (w * 2 + 0) * 8) * K_DIM + (size_t)(kt) * 64,    \
                Bs + (bb) * 16384 + (hh) * 8192 + w * 1024);                                 \
    gload_lds16(gB0 + (size_t)((hh) * 128 + (w * 2 + 1) * 8) * K_DIM + (size_t)(kt) * 64,    \
                Bs + (bb) * 16384 + (hh) * 8192 + w * 1024 + 512);                           \
} while (0)

#define RD_B(bb, ni, ks) (*(const short8*)(Bs + (bb) * 16384 + brow + (ni) * 1024 + col[ks]))

// A-fragment direct loads: 10 x global_load_dwordx4 into aR[par] (par literal!)
#define LD_A(par, kt) do {                                                                   \
    _Pragma("unroll") for (int mi_ = 0; mi_ < 5; ++mi_)                                      \
    _Pragma("unroll") for (int ks_ = 0; ks_ < 2; ++ks_)                                      \
        aR[par][mi_][ks_] = *(const short8*)(gA + (size_t)(mi_ * 16) * K_DIM                 \
                                             + (size_t)(kt) * 64 + ks_ * 32);                \
} while (0)

#define MF(a, b, c) __builtin_amdgcn_mfma_f32_16x16x32_bf16(a, b, c, 0, 0, 0)

// full K-tile: 8 B ds_reads (issue order = consume order), then 40 MFMAs
#define COMPUTE(par) do {                                                                    \
    bq[0][0] = RD_B(par, 0, 0); bq[1][0] = RD_B(par, 1, 0);                                  \
    bq[2][0] = RD_B(par, 2, 0); bq[3][0] = RD_B(par, 3, 0);                                  \
    bq[0][1] = RD_B(par, 0, 1); bq[1][1] = RD_B(par, 1, 1);                                  \
    bq[2][1] = RD_B(par, 2, 1); bq[3][1] = RD_B(par, 3, 1);                                  \
    __builtin_amdgcn_s_setprio(1);                                                           \
    _Pragma("unroll") for (int ks_ = 0; ks_ < 2; ++ks_)                                      \
      _Pragma("unroll") for (int mi_ = 0; mi_ < 5; ++mi_)                                    \
        _Pragma("unroll") for (int ni_ = 0; ni_ < 4; ++ni_)                                  \
          acc[mi_][ni_] = MF(aR[par][mi_][ks_], bq[ni_][ks_], acc[mi_][ni_]);                \
    __builtin_amdgcn_s_setprio(0);                                                           \
} while (0)

#define FENCE() asm volatile("" ::: "memory")
#define BARRIER() do { FENCE(); __builtin_amdgcn_s_barrier(); FENCE(); } while (0)
#define VMW14() asm volatile("s_waitcnt vmcnt(14)" ::: "memory")
#define VMW0()  asm volatile("s_waitcnt vmcnt(0)" ::: "memory")

__global__ __launch_bounds__(512, 2) void gemm_bt(const u16* __restrict__ A,
                                                  const u16* __restrict__ B,
                                                  __hip_bfloat16* __restrict__ C) {
    // B only: 2 buffers x 256 rows x 64 cols bf16 = 64 KiB
    __shared__ __align__(16) u16 Bs[2 * 256 * 64];

    // T1: XCD-aware bijective swizzle (256 % 8 == 0)
    int orig = blockIdx.x;
    int wgid = (orig & 7) * 32 + (orig >> 3);
    int nt = wgid >> 4, mt = wgid & 15;
    int m0 = mt * 160, n0 = nt * 256;

    int t = threadIdx.x;
    int w = t >> 6, L = t & 63;          // wave 0..7, lane
    int wm = w >> 2, wn = w & 3;         // wave grid 2M x 4N, per-wave 80x64
    int q = L >> 4, lm = L & 15;         // MFMA lane decomposition
    int lr = L >> 3, ls = L & 7;         // staging lane decomposition

    // B staging global base (per-lane pre-swizzled column, rule #21)
    int csw = (ls ^ lr) * 8;
    const u16* gB0 = B + (size_t)(n0 + lr) * K_DIM + csw;
    // A direct per-lane base: row = m0 + wm*80 + mi*16 + lm, col = kt*64 + ks*32 + q*8
    const u16* gA = A + (size_t)(m0 + wm * 80 + lm) * K_DIM + q * 8;

    // B ds_read addressing: element (r,c) at r*64 + (c ^ ((r&7)<<3))
    int sw = (lm & 7) << 3;
    int brow = (wn * 64 + lm) * 64;
    int col[2] = { (q * 8) ^ sw, (32 + q * 8) ^ sw };

    floatx4 acc[5][4];
    floatx4 z = {0.f, 0.f, 0.f, 0.f};
#pragma unroll
    for (int i = 0; i < 5; ++i)
#pragma unroll
        for (int j = 0; j < 4; ++j) acc[i][j] = z;

    short8 aR[2][5][2];                  // A frags, double-buffered by tile parity
    short8 bq[4][2];

    // ---- prologue: A(0), Bh(0)->buf0, Bh(1)->buf1, A(1) ----
    LD_A(0, 0);                          // 10
    STG_B(0, 0, 0); STG_B(0, 1, 0);      // 4
    STG_B(1, 0, 1); STG_B(1, 1, 1);      // 4
    LD_A(1, 1);                          // 10  -> 28 outstanding
    VMW14();                             // drain A(0)+Bh(0); keep Bh(1)+A(1)=14
    BARRIER();

    // ---- main loop: T = 2it, 2it+1; stages/loads for T+2, T+3 ----
    for (int it = 0; it < 15; ++it) {
        int T = 2 * it;
        COMPUTE(0);                      // tile T (aR[0], Bs[0])
        BARRIER();                       // all waves done reading Bs[0]
        STG_B(0, 0, T + 2); STG_B(0, 1, T + 2);   // 4 -> buf0
        LD_A(0, T + 2);                  // 10 -> aR[0]
        VMW14();                         // drain Bh(T+1)+A(T+1); keep new 14
        BARRIER();                       // tile T+1 ready for all waves
        COMPUTE(1);                      // tile T+1 (aR[1], Bs[1])
        BARRIER();
        STG_B(1, 0, T + 3); STG_B(1, 1, T + 3);   // 4 -> buf1
        LD_A(1, T + 3);                  // 10 -> aR[1]
        VMW14();                         // drain Bh(T+2)+A(T+2); keep new 14
        BARRIER();                       // tile T+2 ready
    }

    // ---- tail: tiles 30, 31 (staged/loaded by it=14) ----
    COMPUTE(0);                          // tile 30
    VMW0(); BARRIER();                   // Bh(31)+A(31) landed everywhere
    COMPUTE(1);                          // tile 31

    // ---- C-write. C/D layout: col=lane&15, row=(lane>>4)*4+reg ----
    if (m0 + 159 < H_ROWS) {
#pragma unroll
        for (int mi = 0; mi < 5; ++mi) {
            int gm = m0 + wm * 80 + mi * 16 + q * 4;
#pragma unroll
            for (int ni = 0; ni < 4; ++ni) {
                int gn = n0 + wn * 64 + ni * 16 + lm;
#pragma unroll
                for (int r = 0; r < 4; ++r)
                    C[(size_t)(gm + r) * NPIX + gn] = __float2bfloat16(acc[mi][ni][r]);
            }
        }
    } else {
#pragma unroll
        for (int mi = 0; mi < 5; ++mi) {
            int gm = m0 + wm * 80 + mi * 16 + q * 4;
#pragma unroll
            for (int ni = 0; ni < 4; ++ni) {
                int gn = n0 + wn * 64 + ni * 16 + lm;
#pragma unroll
                for (int r = 0; r < 4; ++r) {
                    int row = gm + r;
                    if (row < H_ROWS)
                        C[(size_t)row * NPIX + gn] = __float2bfloat16(acc[mi][ni][r]);
                }
            }
        }
    }
}

// ---------------- sigma_raw (conv rows of H) + BN stats (R7-validated) ----------------
__global__ void sigma_stats(const __hip_bfloat16* __restrict__ Hm, float* __restrict__ sraw,
                            float* __restrict__ stats) {
    int b = blockIdx.x;           // (n*9 + l)*4 + quarter
    int qq = b & 3, nl = b >> 2;
    int n = nl / 9, l = nl - n * 9;
    int t = threadIdx.x;
    int pix = qq * 256 + t;
    int y = pix >> 5, x = pix & 31;
    float v = 0.f;
#pragma unroll
    for (int k = 0; k < 9; ++k) {
        int yy = y + k / 3 - 1, xx = x + (k % 3) - 1;
        if (yy >= 0 && yy < 32 && xx >= 0 && xx < 32)
            v += __bfloat162float(Hm[(size_t)(2304 + k * 9 + l) * NPIX + n * HW + yy * 32 + xx]);
    }
    sraw[(size_t)nl * HW + pix] = v;
    __shared__ float r1[256], r2[256];
    r1[t] = v; r2[t] = v * v;
    __syncthreads();
    for (int s = 128; s > 0; s >>= 1) {
        if (t < s) { r1[t] += r1[t + s]; r2[t] += r2[t + s]; }
        __syncthreads();
    }
    if (t == 0) { atomicAdd(&stats[l], r1[0]); atomicAdd(&stats[9 + l], r2[0]); }
}

// ---------------- tail v3: lane->consecutive pixel (coalesced H reads), 2 o per block, pixel-halves ----------------
// grid 1024: b = n*256 + ph*128 + og; channels o = 2*og,2*og+1; pixels ph*512 + i*256 + t (i=0,1)
__global__ void tail(const __hip_bfloat16* __restrict__ Hm, const float* __restrict__ sraw,
                     const float* __restrict__ stats, const float* __restrict__ gamma,
                     const float* __restrict__ beta, float* __restrict__ out) {
    int b = blockIdx.x;
    int n = b >> 8, rem = b & 255;
    int ph = rem >> 7, og = rem & 127;
    int t = threadIdx.x;
    float mean[9], istd[9], gg[9], bb[9];
#pragma unroll
    for (int l = 0; l < 9; ++l) {
        float m = stats[l] * (1.f / 4096.f);
        float var = stats[9 + l] * (1.f / 4096.f) - m * m;
        mean[l] = m; istd[l] = rsqrtf(var + BN_EPS);
        gg[l] = gamma[l]; bb[l] = beta[l];
    }
    const __hip_bfloat16* hb = Hm + (size_t)(og * 2) * NPIX + (size_t)n * HW;
    float* ob = out + ((size_t)n * 256 + og * 2) * HW;
#pragma unroll
    for (int i = 0; i < 2; ++i) {
        int pix = ph * 512 + i * 256 + t;
        int y = pix >> 5, x = pix & 31;
        float v[9];
        float mx = -1e30f;
#pragma unroll
        for (int l = 0; l < 9; ++l) {
            float tv = (sraw[(size_t)(n * 9 + l) * HW + pix] - mean[l]) * istd[l];
            tv = tv * gg[l] + bb[l];
            v[l] = tv; mx = fmaxf(mx, tv);
        }
        float ssum = 0.f;
#pragma unroll
        for (int l = 0; l < 9; ++l) { v[l] = __expf(v[l] - mx); ssum += v[l]; }
        float inv = 1.f / ssum;
        float acc0 = 0.f, acc1 = 0.f;
#pragma unroll
        for (int l = 0; l < 9; ++l) {
            int dy = l / 3 - 1, dx = l % 3 - 1;
            int yy = y + dy, xx = x + dx;
            if (yy >= 0 && yy < 32 && xx >= 0 && xx < 32) {
                float sv = v[l] * inv;
                size_t hidx = (size_t)(l * 256) * NPIX + (size_t)(pix + dy * 32 + dx);
                acc0 += sv * __bfloat162float(hb[hidx]);
                acc1 += sv * __bfloat162float(hb[hidx + NPIX]);
            }
        }
        ob[pix] = acc0;
        ob[HW + pix] = acc1;
    }
}

extern "C" void kernel_launch(void* const* d_in, const int* in_sizes, int n_in,
                              void* d_out, int out_size, void* d_ws, size_t ws_size,
                              hipStream_t stream) {
    const float* x     = (const float*)d_in[0];
    const float* cw    = (const float*)d_in[1];
    const float* gamma = (const float*)d_in[2];
    const float* beta  = (const float*)d_in[3];
    const float* wgt   = (const float*)d_in[4];

    char* ws = (char*)d_ws;
    u16*   Abuf = (u16*)(ws + OFF_A);
    u16*   XT   = (u16*)(ws + OFF_XT);
    u16*   Hm   = (u16*)(ws + OFF_H);
    float* sraw = (float*)(ws + OFF_SRAW);
    float* stats= (float*)(ws + OFF_STAT);

    build_all<<<2314, 256, 0, stream>>>(x, wgt, cw, XT, Abuf, stats);
    gemm_bt<<<256, 512, 0, stream>>>(Abuf, XT, (__hip_bfloat16*)Hm);
    sigma_stats<<<N_IMG * KK * 4, 256, 0, stream>>>((const __hip_bfloat16*)Hm, sraw, stats);
    tail<<<1024, 256, 0, stream>>>((const __hip_bfloat16*)Hm, sraw, stats, gamma, beta, (float*)d_out);
}

// Round 6
// 156.967 us; speedup vs baseline: 1.3459x; 1.3459x over previous
//
#include <hip/hip_runtime.h>
#include <hip/hip_bf16.h>
#include <stdint.h>

typedef unsigned short u16;
typedef __attribute__((ext_vector_type(8))) short short8;
typedef __attribute__((ext_vector_type(4))) float floatx4;

#define N_IMG 4
#define C_IN  2048
#define HW    1024
#define KK    9
#define O_OUT 256
#define NPIX  4096          // N_IMG*HW
#define M_PAD  2560         // 16 M-tiles x 160 rows (2304 proj + 81 conv + pad)
#define H_ROWS 2432         // H rows actually stored (proj 2304 + conv 81 + pad)
#define K_DIM  2048
#define BN_EPS 1e-5f

// workspace offsets (bytes), 256-aligned
#define OFF_A    0u                // A: 2560*2048*2 = 10485760
#define OFF_XT   10485760u         // XT: 4096*2048*2 = 16777216
#define OFF_H    27262976u         // H: 2432*4096*2 = 19922944
#define OFF_SRAW 47185920u         // sraw: 36864*4
#define OFF_STAT 47333376u

// fp32 -> bf16 bits, round-to-nearest-even
__device__ __forceinline__ u16 f2b(float f) {
    unsigned u = __float_as_uint(f);
    return (u16)((u + 0x7FFFu + ((u >> 16) & 1u)) >> 16);
}

__device__ __forceinline__ void load8f(const float* base, size_t eidx, u16* out) {
    const float* p = base + eidx;
    float4 a = ((const float4*)p)[0];
    float4 b = ((const float4*)p)[1];
    float f[8] = {a.x, a.y, a.z, a.w, b.x, b.y, b.z, b.w};
#pragma unroll
    for (int j = 0; j < 8; ++j) out[j] = f2b(f[j]);
}

// ---------------- merged staging kernel (R10-validated, unchanged) ----------------
__global__ void build_all(const float* __restrict__ x, const float* __restrict__ wgt,
                          const float* __restrict__ cw, u16* __restrict__ xt,
                          u16* __restrict__ A, float* __restrict__ stats) {
    __shared__ __align__(16) u16 lds[9 * 2056];
    int b = blockIdx.x, t = threadIdx.x;
    if (b < 2048) {
        int c0 = (b & 31) * 64, p0 = ((b >> 5) & 15) * 64, n = b >> 9;
        int rp = t >> 3;                // channel-pair 0..31
        int pv = (t & 7) * 8;           // pixel group
        u16 h0[8], h1[8];
        load8f(x, (size_t)(n * C_IN + c0 + 2 * rp) * HW + p0 + pv, h0);
        load8f(x, (size_t)(n * C_IN + c0 + 2 * rp + 1) * HW + p0 + pv, h1);
        unsigned* l32 = (unsigned*)lds;   // [64 pixels][stride 35 u32]
#pragma unroll
        for (int j = 0; j < 8; ++j)
            l32[(pv + j) * 35 + rp] = (unsigned)h0[j] | ((unsigned)h1[j] << 16);
        __syncthreads();
        int pr = t >> 3, cq = (t & 7) * 4;   // pixel, u32-quad (8 channels)
        unsigned o0[4], o1[4];
#pragma unroll
        for (int i = 0; i < 4; ++i) {
            o0[i] = l32[pr * 35 + cq + i];
            o1[i] = l32[(pr + 32) * 35 + cq + i];
        }
        *(uint4*)(xt + (size_t)(n * HW + p0 + pr) * K_DIM + c0 + cq * 2) = *(uint4*)o0;
        *(uint4*)(xt + (size_t)(n * HW + p0 + pr + 32) * K_DIM + c0 + cq * 2) = *(uint4*)o1;
    } else if (b < 2304) {
        int o = b - 2048;
        size_t base = (size_t)o * 18432;   // weight[o][c][l], e = c*9+l
        for (int i = 0; i < 9; ++i) {
            int e0 = (t + i * 256) * 8;
            u16 hv[8];
            load8f(wgt, base + e0, hv);
#pragma unroll
            for (int j = 0; j < 8; ++j) {
                int e = e0 + j;
                int c = e / 9, l = e - c * 9;
                lds[l * 2056 + c] = hv[j];
            }
        }
        __syncthreads();
        for (int l = 0; l < 9; ++l) {
            size_t row = (size_t)l * 256 + o;
            *(uint4*)(A + row * K_DIM + t * 8) = *(const uint4*)&lds[l * 2056 + t * 8];
        }
    } else if (b < 2313) {
        int l = b - 2304;
        size_t base = (size_t)l * 18432;    // conv_w[l][c][k], e = c*9+k
        for (int i = 0; i < 9; ++i) {
            int e0 = (t + i * 256) * 8;
            u16 hv[8];
            load8f(cw, base + e0, hv);
#pragma unroll
            for (int j = 0; j < 8; ++j) {
                int e = e0 + j;
                int c = e / 9, k = e - c * 9;
                lds[k * 2056 + c] = hv[j];
            }
        }
        __syncthreads();
        for (int k = 0; k < 9; ++k) {
            size_t row = 2304 + (size_t)k * 9 + l;
            *(uint4*)(A + row * K_DIM + t * 8) = *(const uint4*)&lds[k * 2056 + t * 8];
        }
    } else {
        // zero A rows 2385..2431 (rows 2432..2559 are garbage; each H row
        // depends only on its own A row and rows >=2432 are never stored;
        // garbage/valid rows never share an MFMA fragment since 2432%16==0)
        uint4 z = {0, 0, 0, 0};
        uint4* dst = (uint4*)(A + (size_t)2385 * K_DIM);
        for (int i = t; i < (47 * 2048) / 8; i += 256) dst[i] = z;
        if (t < 18) stats[t] = 0.0f;
    }
}

// ---------------- GEMM: H = A * XT^T ----------------
// R16: 160x128 tile, BK=64, 4 waves (2Mx2N, per-wave 80x64), grid 16x32=512
// -> 2 independent blocks per CU (LDS 72KB/block, launch_bounds(256,2)).
// Rationale: R1/R3/R4 showed per-CU efficiency tracks LDS-bytes-per-FLOP and
// single-block barrier lockstep serializes read-bursts vs MFMA-bursts
// (~1.7x over resource bound). Two co-resident blocks are never
// barrier-coupled: one block's MFMAs cover the other's read/stage/DMA-wait
// windows. Protocol = R3's validated counted-vmcnt ledger resized:
// VMW9 = keep newest stage pair (B[4]+A[5]), drains the previous pair.
__device__ __forceinline__ void gload_lds16(const void* g, void* l) {
    __builtin_amdgcn_global_load_lds((__attribute__((address_space(1))) void*)(g),
                                     (__attribute__((address_space(3))) void*)(l), 16, 0, 0);
}

// A tile = 160 rows x 64 cols = 20 quanta (8 rows each); wave w stages
// quanta w, w+4, w+8, w+12, w+16. LDS dest linear; global col pre-swizzled.
#define STG_A(bb, kt) do {                                                                   \
    _Pragma("unroll") for (int j_ = 0; j_ < 5; ++j_) {                                       \
        int qd_ = w + 4 * j_;                                                                \
        gload_lds16(gA0 + (size_t)(qd_ * 8) * K_DIM + (size_t)(kt) * 64,                     \
                    As + (bb) * 10240 + qd_ * 512);                                          \
    }                                                                                        \
} while (0)

// B tile = 128 rows x 64 cols = 16 quanta; wave w stages w, w+4, w+8, w+12
#define STG_B(bb, kt) do {                                                                   \
    _Pragma("unroll") for (int j_ = 0; j_ < 4; ++j_) {                                       \
        int qd_ = w + 4 * j_;                                                                \
        gload_lds16(gB0 + (size_t)(qd_ * 8) * K_DIM + (size_t)(kt) * 64,                     \
                    Bs + (bb) * 8192 + qd_ * 512);                                           \
    }                                                                                        \
} while (0)

#define RD_A(bb, mi, ks) (*(const short8*)(As + (bb) * 10240 + arow + (mi) * 1024 + col[ks]))
#define RD_B(bb, ni, ks) (*(const short8*)(Bs + (bb) * 8192 + brow + (ni) * 1024 + col[ks]))

#define MF(a, b, c) __builtin_amdgcn_mfma_f32_16x16x32_bf16(a, b, c, 0, 0, 0)

// full K-tile: 18 ds_reads (issue order = consume order, ks-outer), 40 MFMAs
#define COMPUTE(par) do {                                                                    \
    bq[0][0] = RD_B(par, 0, 0); bq[1][0] = RD_B(par, 1, 0);                                  \
    bq[2][0] = RD_B(par, 2, 0); bq[3][0] = RD_B(par, 3, 0);                                  \
    aq[0][0] = RD_A(par, 0, 0); aq[1][0] = RD_A(par, 1, 0);                                  \
    aq[2][0] = RD_A(par, 2, 0); aq[3][0] = RD_A(par, 3, 0);                                  \
    aq[4][0] = RD_A(par, 4, 0);                                                              \
    bq[0][1] = RD_B(par, 0, 1); bq[1][1] = RD_B(par, 1, 1);                                  \
    bq[2][1] = RD_B(par, 2, 1); bq[3][1] = RD_B(par, 3, 1);                                  \
    aq[0][1] = RD_A(par, 0, 1); aq[1][1] = RD_A(par, 1, 1);                                  \
    aq[2][1] = RD_A(par, 2, 1); aq[3][1] = RD_A(par, 3, 1);                                  \
    aq[4][1] = RD_A(par, 4, 1);                                                              \
    __builtin_amdgcn_s_setprio(1);                                                           \
    _Pragma("unroll") for (int ks_ = 0; ks_ < 2; ++ks_)                                      \
      _Pragma("unroll") for (int mi_ = 0; mi_ < 5; ++mi_)                                    \
        _Pragma("unroll") for (int ni_ = 0; ni_ < 4; ++ni_)                                  \
          acc[mi_][ni_] = MF(aq[mi_][ks_], bq[ni_][ks_], acc[mi_][ni_]);                     \
    __builtin_amdgcn_s_setprio(0);                                                           \
} while (0)

#define FENCE() asm volatile("" ::: "memory")
#define BARRIER() do { FENCE(); __builtin_amdgcn_s_barrier(); FENCE(); } while (0)
#define VMW9() asm volatile("s_waitcnt vmcnt(9)" ::: "memory")
#define VMW0() asm volatile("s_waitcnt vmcnt(0)" ::: "memory")

__global__ __launch_bounds__(256, 2) void gemm_bt(const u16* __restrict__ A,
                                                  const u16* __restrict__ B,
                                                  __hip_bfloat16* __restrict__ C) {
    // A: 2 x 160 x 64 bf16 = 40 KiB; B: 2 x 128 x 64 bf16 = 32 KiB -> 72 KiB
    __shared__ __align__(16) u16 As[2 * 160 * 64];
    __shared__ __align__(16) u16 Bs[2 * 128 * 64];

    // T1: XCD-aware bijective swizzle (512 % 8 == 0); nt-major chunks/XCD
    int orig = blockIdx.x;
    int wgid = (orig & 7) * 64 + (orig >> 3);
    int nt = wgid >> 4, mt = wgid & 15;    // nt 0..31, mt 0..15
    int m0 = mt * 160, n0 = nt * 128;

    int t = threadIdx.x;
    int w = t >> 6, L = t & 63;          // wave 0..3, lane
    int wm = w >> 1, wn = w & 1;         // wave grid 2M x 2N, per-wave 80x64
    int q = L >> 4, lm = L & 15;         // MFMA lane decomposition
    int lr = L >> 3, ls = L & 7;         // staging lane decomposition

    // staging global base (per-lane pre-swizzled column, rule #21)
    int csw = (ls ^ lr) * 8;
    const u16* gA0 = A + (size_t)(m0 + lr) * K_DIM + csw;
    const u16* gB0 = B + (size_t)(n0 + lr) * K_DIM + csw;

    // ds_read addressing: element (r,c) at r*64 + (c ^ ((r&7)<<3))
    int sw = (lm & 7) << 3;
    int arow = (wm * 80 + lm) * 64;      // 80 % 16 == 0 so (r&7) == (lm&7)
    int brow = (wn * 64 + lm) * 64;
    int col[2] = { (q * 8) ^ sw, (32 + q * 8) ^ sw };

    floatx4 acc[5][4];
    floatx4 z = {0.f, 0.f, 0.f, 0.f};
#pragma unroll
    for (int i = 0; i < 5; ++i)
#pragma unroll
        for (int j = 0; j < 4; ++j) acc[i][j] = z;

    short8 aq[5][2], bq[4][2];

    // ---- prologue: tile0 -> buf0, tile1 -> buf1 (left in flight) ----
    STG_A(0, 0); STG_B(0, 0);            // 9
    STG_B(1, 1); STG_A(1, 1);            // 9 -> 18 outstanding
    VMW9();                              // drain tile0 (A+B); keep tile1's 9
    BARRIER();

    // ---- main loop: it = 0..14, tiles T=2it (buf0), T+1 (buf1) ----
    for (int it = 0; it < 15; ++it) {
        int T = 2 * it;
        COMPUTE(0);                      // tile T from buf0
        BARRIER();                       // all waves done reading buf0
        if (it < 15) { }                 // (uniform: stages below always valid, T+3<=31)
        STG_B(0, T + 2); STG_A(0, T + 2);   // 9 -> buf0
        VMW9();                          // drain tile T+1's 9; keep new 9
        BARRIER();                       // tile T+1 ready for all waves
        COMPUTE(1);                      // tile T+1 from buf1
        BARRIER();
        if (it < 14) {
            STG_B(1, T + 3); STG_A(1, T + 3);  // 9 -> buf1
            VMW9();                      // drain tile T+2's 9; keep new 9
            BARRIER();                   // tile T+2 ready
        }
    }
    // after it=14: tiles 0..29 computed; tile 30 staged (buf0, it=14 first
    // stage); 9 outstanding = tile-30 stage... ledger: it=14 staged T+2=30
    // into buf0 (VMW9 drained tile 29's stage; kept tile 30's 9). Loop
    // skipped the second stage. Outstanding now: tile30's 9.
    VMW0(); BARRIER();                   // tile 30 landed everywhere
    COMPUTE(0);                          // tile 30
    BARRIER();
    STG_B(1, 31); STG_A(1, 31);          // stage tile 31 -> buf1
    VMW0(); BARRIER();                   // tile 31 landed
    COMPUTE(1);                          // tile 31

    // ---- C-write. C/D layout: col=lane&15, row=(lane>>4)*4+reg ----
    if (m0 + 159 < H_ROWS) {
#pragma unroll
        for (int mi = 0; mi < 5; ++mi) {
            int gm = m0 + wm * 80 + mi * 16 + q * 4;
#pragma unroll
            for (int ni = 0; ni < 4; ++ni) {
                int gn = n0 + wn * 64 + ni * 16 + lm;
#pragma unroll
                for (int r = 0; r < 4; ++r)
                    C[(size_t)(gm + r) * NPIX + gn] = __float2bfloat16(acc[mi][ni][r]);
            }
        }
    } else {
#pragma unroll
        for (int mi = 0; mi < 5; ++mi) {
            int gm = m0 + wm * 80 + mi * 16 + q * 4;
#pragma unroll
            for (int ni = 0; ni < 4; ++ni) {
                int gn = n0 + wn * 64 + ni * 16 + lm;
#pragma unroll
                for (int r = 0; r < 4; ++r) {
                    int row = gm + r;
                    if (row < H_ROWS)
                        C[(size_t)row * NPIX + gn] = __float2bfloat16(acc[mi][ni][r]);
                }
            }
        }
    }
}

// ---------------- sigma_raw (conv rows of H) + BN stats (R7-validated) ----------------
__global__ void sigma_stats(const __hip_bfloat16* __restrict__ Hm, float* __restrict__ sraw,
                            float* __restrict__ stats) {
    int b = blockIdx.x;           // (n*9 + l)*4 + quarter
    int qq = b & 3, nl = b >> 2;
    int n = nl / 9, l = nl - n * 9;
    int t = threadIdx.x;
    int pix = qq * 256 + t;
    int y = pix >> 5, x = pix & 31;
    float v = 0.f;
#pragma unroll
    for (int k = 0; k < 9; ++k) {
        int yy = y + k / 3 - 1, xx = x + (k % 3) - 1;
        if (yy >= 0 && yy < 32 && xx >= 0 && xx < 32)
            v += __bfloat162float(Hm[(size_t)(2304 + k * 9 + l) * NPIX + n * HW + yy * 32 + xx]);
    }
    sraw[(size_t)nl * HW + pix] = v;
    __shared__ float r1[256], r2[256];
    r1[t] = v; r2[t] = v * v;
    __syncthreads();
    for (int s = 128; s > 0; s >>= 1) {
        if (t < s) { r1[t] += r1[t + s]; r2[t] += r2[t + s]; }
        __syncthreads();
    }
    if (t == 0) { atomicAdd(&stats[l], r1[0]); atomicAdd(&stats[9 + l], r2[0]); }
}

// ---------------- tail v3: lane->consecutive pixel (coalesced H reads), 2 o per block, pixel-halves ----------------
// grid 1024: b = n*256 + ph*128 + og; channels o = 2*og,2*og+1; pixels ph*512 + i*256 + t (i=0,1)
__global__ void tail(const __hip_bfloat16* __restrict__ Hm, const float* __restrict__ sraw,
                     const float* __restrict__ stats, const float* __restrict__ gamma,
                     const float* __restrict__ beta, float* __restrict__ out) {
    int b = blockIdx.x;
    int n = b >> 8, rem = b & 255;
    int ph = rem >> 7, og = rem & 127;
    int t = threadIdx.x;
    float mean[9], istd[9], gg[9], bb[9];
#pragma unroll
    for (int l = 0; l < 9; ++l) {
        float m = stats[l] * (1.f / 4096.f);
        float var = stats[9 + l] * (1.f / 4096.f) - m * m;
        mean[l] = m; istd[l] = rsqrtf(var + BN_EPS);
        gg[l] = gamma[l]; bb[l] = beta[l];
    }
    const __hip_bfloat16* hb = Hm + (size_t)(og * 2) * NPIX + (size_t)n * HW;
    float* ob = out + ((size_t)n * 256 + og * 2) * HW;
#pragma unroll
    for (int i = 0; i < 2; ++i) {
        int pix = ph * 512 + i * 256 + t;
        int y = pix >> 5, x = pix & 31;
        float v[9];
        float mx = -1e30f;
#pragma unroll
        for (int l = 0; l < 9; ++l) {
            float tv = (sraw[(size_t)(n * 9 + l) * HW + pix] - mean[l]) * istd[l];
            tv = tv * gg[l] + bb[l];
            v[l] = tv; mx = fmaxf(mx, tv);
        }
        float ssum = 0.f;
#pragma unroll
        for (int l = 0; l < 9; ++l) { v[l] = __expf(v[l] - mx); ssum += v[l]; }
        float inv = 1.f / ssum;
        float acc0 = 0.f, acc1 = 0.f;
#pragma unroll
        for (int l = 0; l < 9; ++l) {
            int dy = l / 3 - 1, dx = l % 3 - 1;
            int yy = y + dy, xx = x + dx;
            if (yy >= 0 && yy < 32 && xx >= 0 && xx < 32) {
                float sv = v[l] * inv;
                size_t hidx = (size_t)(l * 256) * NPIX + (size_t)(pix + dy * 32 + dx);
                acc0 += sv * __bfloat162float(hb[hidx]);
                acc1 += sv * __bfloat162float(hb[hidx + NPIX]);
            }
        }
        ob[pix] = acc0;
        ob[HW + pix] = acc1;
    }
}

extern "C" void kernel_launch(void* const* d_in, const int* in_sizes, int n_in,
                              void* d_out, int out_size, void* d_ws, size_t ws_size,
                              hipStream_t stream) {
    const float* x     = (const float*)d_in[0];
    const float* cw    = (const float*)d_in[1];
    const float* gamma = (const float*)d_in[2];
    const float* beta  = (const float*)d_in[3];
    const float* wgt   = (const float*)d_in[4];

    char* ws = (char*)d_ws;
    u16*   Abuf = (u16*)(ws + OFF_A);
    u16*   XT   = (u16*)(ws + OFF_XT);
    u16*   Hm   = (u16*)(ws + OFF_H);
    float* sraw = (float*)(ws + OFF_SRAW);
    float* stats= (float*)(ws + OFF_STAT);

    build_all<<<2314, 256, 0, stream>>>(x, wgt, cw, XT, Abuf, stats);
    gemm_bt<<<512, 256, 0, stream>>>(Abuf, XT, (__hip_bfloat16*)Hm);
    sigma_stats<<<N_IMG * KK * 4, 256, 0, stream>>>((const __hip_bfloat16*)Hm, sraw, stats);
    tail<<<1024, 256, 0, stream>>>((const __hip_bfloat16*)Hm, sraw, stats, gamma, beta, (float*)d_out);
}